// Round 5
// baseline (284.046 us; speedup 1.0000x reference)
//
#include <hip/hip_runtime.h>
#include <hip/hip_bf16.h>

typedef __attribute__((ext_vector_type(4))) float f32x4;
typedef __attribute__((ext_vector_type(8))) short bf16x8;

#define H 1024        // hidden / K
#define NTOT 1280     // nq*64 + nkv*64*2
#define BM 256
#define BN 256
#define BK 64
#define NKT 16        // H / BK

static __device__ __forceinline__ unsigned short f2bf(float f) {
    __hip_bfloat16 b = __float2bfloat16(f);
    return __builtin_bit_cast(unsigned short, b);
}

#define GLOAD_LDS16(g, l)                                                     \
    __builtin_amdgcn_global_load_lds(                                         \
        (const __attribute__((address_space(1))) void*)(g),                   \
        (__attribute__((address_space(3))) void*)(l), 16, 0, 0)

// ---------------------------------------------------------------------------
// Kernel 1: build transposed fused weight Bt[n][k] = bf16((1+lnw[k]) * W[k][n])
// ---------------------------------------------------------------------------
__global__ __launch_bounds__(256) void k_wprep(const float* __restrict__ wq,
                                               const float* __restrict__ wk,
                                               const float* __restrict__ wv,
                                               const float* __restrict__ lnw,
                                               __hip_bfloat16* __restrict__ Bt) {
    const int idx = blockIdx.x * 256 + threadIdx.x;  // idx = n*1024 + k
    const int n = idx >> 10;
    const int k = idx & 1023;
    const float s = 1.0f + lnw[k];
    float w;
    if (n < 1024)       w = wq[k * 1024 + n];
    else if (n < 1152)  w = wk[k * 128 + (n - 1024)];
    else                w = wv[k * 128 + (n - 1152)];
    Bt[idx] = __float2bfloat16(s * w);
}

// ---------------------------------------------------------------------------
// Kernel 2: FUSED RMSNorm + GEMM.  out[M][1280] = diag(s) . (bf16(x) @ Bt^T)
// where s_r = rsqrt(mean(x_r^2)+eps) — scale commutes with the linear map, so
// it is applied in the epilogue; sum(x^2) is accumulated during A-staging.
// 256x256 tile, BK=64, 8 waves, ring-2 LDS, ONE barrier per K-tile (waves
// drift: reads(kt+1) overlap MFMA(kt) across waves). A: fp32 global -> reg ->
// cvt bf16 -> swizzled ds_write. B: global_load_lds, source pre-swizzled.
// Waits: vmcnt(8)+lgkm(0) pre-barrier (forces B(kt+1); keeps A(kt+2),B(kt+2)
// in flight). cvt's A-reg dependency gets a compiler-counted vmcnt (forces
// the older B tile too). Tail kt=14 drains with vmcnt(0).
// ---------------------------------------------------------------------------
__global__ __launch_bounds__(512, 2) void k_gemm(const float* __restrict__ X,
                                                 const __hip_bfloat16* __restrict__ Bt,
                                                 float* __restrict__ out, int rows) {
    __shared__ __align__(16) char smem[131072];  // 2 bufs x (A 32KB | B 32KB)
    __shared__ float s_lds[BM];

    const int tid = threadIdx.x;
    const int lane = tid & 63;
    const int wid = tid >> 6;
    const int wm = wid >> 2;   // 0..1
    const int wn = wid & 3;    // 0..3

    // bijective XCD chunk swizzle, nt fastest (A-strip sharers on one XCD L2)
    const int nwg = gridDim.x;
    const int q8 = nwg >> 3, r8 = nwg & 7;
    const int xcd = blockIdx.x & 7, rank = blockIdx.x >> 3;
    const int wg = (xcd < r8 ? xcd * (q8 + 1) : r8 * (q8 + 1) + (xcd - r8) * q8) + rank;
    const int nt = wg % (NTOT / BN);   // 0..4
    const int mt = wg / (NTOT / BN);
    const size_t m0 = (size_t)mt * BM;

    // ---- staging geometry: thread t covers rows rq+q*64 (q=0..3), 8 cols ----
    const int rq = tid >> 3;                    // 0..63
    const int c8 = (tid & 7) * 8;               // float col within K-tile
    const float* xbase = X + (m0 + rq) * (size_t)H + c8;
    // A LDS dest (bf16): row-major [256][128B], col swizzled ^((row&7)<<4)
    const int adst = rq * 128 + (((tid & 7) * 16) ^ ((rq & 7) << 4));
    // B staging: linear LDS dest, source col pre-swizzled (involution, rule 21)
    const int cswz = ((tid & 7) * 16) ^ ((rq & 7) << 4);
    const char* bG = (const char*)Bt + ((size_t)nt * BN + rq) * (size_t)(H * 2) + cswz;

    float4 va[8];      // in-flight A fp32 (32 floats)
    float ss[4] = {0.f, 0.f, 0.f, 0.f};

#define A_ISSUE(kt)                                                           \
    _Pragma("unroll") for (int q = 0; q < 4; ++q) {                           \
        va[q * 2]     = *(const float4*)(xbase + (size_t)(kt) * 64 + (size_t)q * 64 * H); \
        va[q * 2 + 1] = *(const float4*)(xbase + (size_t)(kt) * 64 + (size_t)q * 64 * H + 4); \
    }

#define A_CVTWRITE(buf)                                                       \
    _Pragma("unroll") for (int q = 0; q < 4; ++q) {                           \
        float4 f0 = va[q * 2], f1 = va[q * 2 + 1];                            \
        ss[q] += f0.x * f0.x + f0.y * f0.y + f0.z * f0.z + f0.w * f0.w;       \
        ss[q] += f1.x * f1.x + f1.y * f1.y + f1.z * f1.z + f1.w * f1.w;       \
        bf16x8 pk;                                                            \
        pk[0] = f2bf(f0.x); pk[1] = f2bf(f0.y); pk[2] = f2bf(f0.z); pk[3] = f2bf(f0.w); \
        pk[4] = f2bf(f1.x); pk[5] = f2bf(f1.y); pk[6] = f2bf(f1.z); pk[7] = f2bf(f1.w); \
        *(bf16x8*)(smem + (size_t)(buf) * 65536 + adst + q * 8192) = pk;      \
    }

#define STAGE_B(buf, kt)                                                      \
    _Pragma("unroll") for (int q = 0; q < 4; ++q)                             \
        GLOAD_LDS16(bG + (size_t)(kt) * (BK * 2) + (size_t)q * 64 * (H * 2),  \
                    smem + (buf) * 65536 + 32768 + q * 8192 + tid * 16);

    // ---- fragment read addressing (swizzled) ----
    const int rowA = wm * 128 + (lane & 15);
    const int rowB = wn * 64 + (lane & 15);
    const int xm = (lane & 7) << 4;
    const int c0 = (((lane >> 4) * 16)) ^ xm;        // kk=0 col bytes
    const int c1 = (64 + ((lane >> 4) * 16)) ^ xm;   // kk=1 col bytes

    f32x4 acc[8][4] = {};

#define COMPUTE(cur)                                                          \
    {                                                                         \
        const char* aL = smem + (cur) * 65536;                                \
        const char* bL = aL + 32768;                                          \
        bf16x8 b0[4];                                                         \
        _Pragma("unroll") for (int ni = 0; ni < 4; ++ni)                      \
            b0[ni] = *(const bf16x8*)(bL + (rowB + ni * 16) * 128 + c0);      \
        _Pragma("unroll") for (int mi = 0; mi < 8; ++mi) {                    \
            bf16x8 a = *(const bf16x8*)(aL + (rowA + mi * 16) * 128 + c0);    \
            _Pragma("unroll") for (int ni = 0; ni < 4; ++ni)                  \
                acc[mi][ni] = __builtin_amdgcn_mfma_f32_16x16x32_bf16(        \
                    a, b0[ni], acc[mi][ni], 0, 0, 0);                         \
        }                                                                     \
        bf16x8 b1[4];                                                         \
        _Pragma("unroll") for (int ni = 0; ni < 4; ++ni)                      \
            b1[ni] = *(const bf16x8*)(bL + (rowB + ni * 16) * 128 + c1);      \
        _Pragma("unroll") for (int mi = 0; mi < 8; ++mi) {                    \
            bf16x8 a = *(const bf16x8*)(aL + (rowA + mi * 16) * 128 + c1);    \
            _Pragma("unroll") for (int ni = 0; ni < 4; ++ni)                  \
                acc[mi][ni] = __builtin_amdgcn_mfma_f32_16x16x32_bf16(        \
                    a, b1[ni], acc[mi][ni], 0, 0, 0);                         \
        }                                                                     \
    }

#define TILE(cur, kt, DS, VM)                                                 \
    {                                                                         \
        if (DS) A_ISSUE((kt) + 2);                                            \
        COMPUTE(cur);                                                         \
        asm volatile("s_waitcnt vmcnt(" VM ") lgkmcnt(0)" ::: "memory");      \
        __builtin_amdgcn_sched_barrier(0);                                    \
        __builtin_amdgcn_s_barrier();                                         \
        __builtin_amdgcn_sched_barrier(0);                                    \
        if (DS) { STAGE_B(cur, (kt) + 2); A_CVTWRITE(cur); }                  \
    }

    // ---- prologue: stage tiles 0 and 1 ----
    A_ISSUE(0); STAGE_B(0, 0);
    A_CVTWRITE(0);                 // auto-vmcnt waits A(0)
    A_ISSUE(1); STAGE_B(1, 1);
    A_CVTWRITE(1);                 // auto-vmcnt waits A(1), forces B(0)
    asm volatile("s_waitcnt lgkmcnt(0)" ::: "memory");
    __builtin_amdgcn_sched_barrier(0);
    __builtin_amdgcn_s_barrier();
    __builtin_amdgcn_sched_barrier(0);

    // ---- main loop: one barrier per K-tile ----
    for (int kt = 0; kt < NKT - 2; kt += 2) {
        TILE(0, kt, 1, "8");
        TILE(1, kt + 1, 1, "8");
    }
    TILE(0, NKT - 2, 0, "0");      // drains B(15)
    TILE(1, NKT - 1, 0, "0");

    // ---- row scales: reduce sum(x^2) across each row's 8 staging lanes ----
#pragma unroll
    for (int q = 0; q < 4; ++q) {
        float s = ss[q];
        s += __shfl_xor(s, 1);
        s += __shfl_xor(s, 2);
        s += __shfl_xor(s, 4);
        s_lds[(tid >> 3) + q * 64] = rsqrtf(s * (1.0f / H) + 1e-6f);
    }
    __syncthreads();

    // ---- epilogue: scale by s_r, split q/k/v regions ----
    const size_t QSZ = (size_t)rows * 1024;
    const size_t KSZ = (size_t)rows * 128;
    const int colg0 = nt * BN + wn * 64;
    float* op;
    int ldc, cb0;
    if (colg0 < 1024)      { op = out;             ldc = 1024; cb0 = colg0; }
    else if (colg0 < 1152) { op = out + QSZ;       ldc = 128;  cb0 = colg0 - 1024; }
    else                   { op = out + QSZ + KSZ; ldc = 128;  cb0 = colg0 - 1152; }

    const int rl0 = wm * 128 + ((lane >> 4) * 4);
    const size_t r0 = m0 + rl0;
    const int cc0 = cb0 + (lane & 15);
#pragma unroll
    for (int mi = 0; mi < 8; ++mi)
#pragma unroll
        for (int r = 0; r < 4; ++r) {
            const float sc = s_lds[rl0 + mi * 16 + r];
#pragma unroll
            for (int ni = 0; ni < 4; ++ni)
                op[(r0 + mi * 16 + r) * (size_t)ldc + cc0 + ni * 16] =
                    acc[mi][ni][r] * sc;
        }
}

// ---------------------------------------------------------------------------
extern "C" void kernel_launch(void* const* d_in, const int* in_sizes, int n_in,
                              void* d_out, int out_size, void* d_ws, size_t ws_size,
                              hipStream_t stream) {
    const float* x   = (const float*)d_in[0];
    const float* lnw = (const float*)d_in[1];
    const float* wq  = (const float*)d_in[2];
    const float* wk  = (const float*)d_in[3];
    const float* wv  = (const float*)d_in[4];
    float* out = (float*)d_out;

    const int rows = in_sizes[0] / H;  // B*S = 32768

    __hip_bfloat16* Bt = (__hip_bfloat16*)d_ws;  // 1280*1024*2 = 2.62 MB

    k_wprep<<<NTOT * H / 256, 256, 0, stream>>>(wq, wk, wv, lnw, Bt);
    k_gemm<<<(rows / BM) * (NTOT / BN), 512, 0, stream>>>(x, Bt, out, rows);
}

// Round 6
// 220.428 us; speedup vs baseline: 1.2886x; 1.2886x over previous
//
#include <hip/hip_runtime.h>
#include <hip/hip_bf16.h>

typedef __attribute__((ext_vector_type(4))) float f32x4;
typedef __attribute__((ext_vector_type(8))) short bf16x8;

#define H 1024        // hidden / K
#define NTOT 1280     // nq*64 + nkv*64*2
#define BM 256
#define BN 128
#define BK 64
#define NKT 16        // H / BK
#define NTILES 10     // NTOT / BN

static __device__ __forceinline__ unsigned short f2bf(float f) {
    __hip_bfloat16 b = __float2bfloat16(f);
    return __builtin_bit_cast(unsigned short, b);
}

#define GLOAD_LDS16(g, l)                                                     \
    __builtin_amdgcn_global_load_lds(                                         \
        (const __attribute__((address_space(1))) void*)(g),                   \
        (__attribute__((address_space(3))) void*)(l), 16, 0, 0)

// ---------------------------------------------------------------------------
// Kernel 1: build transposed fused weight Bt[n][k] = bf16((1+lnw[k]) * W[k][n])
// ---------------------------------------------------------------------------
__global__ __launch_bounds__(256) void k_wprep(const float* __restrict__ wq,
                                               const float* __restrict__ wk,
                                               const float* __restrict__ wv,
                                               const float* __restrict__ lnw,
                                               __hip_bfloat16* __restrict__ Bt) {
    const int idx = blockIdx.x * 256 + threadIdx.x;  // idx = n*1024 + k
    const int n = idx >> 10;
    const int k = idx & 1023;
    const float s = 1.0f + lnw[k];
    float w;
    if (n < 1024)       w = wq[k * 1024 + n];
    else if (n < 1152)  w = wk[k * 128 + (n - 1024)];
    else                w = wv[k * 128 + (n - 1152)];
    Bt[idx] = __float2bfloat16(s * w);
}

// ---------------------------------------------------------------------------
// Kernel 2: FUSED RMSNorm + GEMM. out = diag(rsqrt(mean(x^2)+eps)) . (x @ BtW)
// (row scale commutes with the linear map -> applied in epilogue; sum(x^2)
// accumulated during A-staging).
// 16 waves (1024 thr, 4x4 wave grid, 4 waves/SIMD), BM=256 BN=128 BK=64,
// ring-2 LDS 96KB, one barrier per K-tile (waves drift), T2 both-sides
// swizzle, counted vmcnt(4) (A(kt+2) loads stay in flight), XCD chunking,
// grid 1280 = 5.0 exact CU-rounds.
// Per-wave: 64x32 output, acc[4][2]=32 AGPR; va[4]=16 VGPR for A reg-staging.
// ---------------------------------------------------------------------------
__global__ __launch_bounds__(1024, 4) void k_gemm(const float* __restrict__ X,
                                                  const __hip_bfloat16* __restrict__ Bt,
                                                  float* __restrict__ out, int rows) {
    __shared__ __align__(16) char smem[98304];  // 2 bufs x (A 32KB | B 16KB)
    __shared__ float s_lds[BM];

    const int tid = threadIdx.x;
    const int lane = tid & 63;
    const int wid = tid >> 6;
    const int wm = wid >> 2;   // 0..3 (rows, 64 each)
    const int wn = wid & 3;    // 0..3 (cols, 32 each)

    // bijective XCD chunk swizzle, nt fastest (1280 % 8 == 0 -> simple)
    const int nwg = gridDim.x;
    const int cpx = nwg >> 3;                       // 160
    const int wg = (blockIdx.x & 7) * cpx + (blockIdx.x >> 3);
    const int nt = wg % NTILES;
    const int mt = wg / NTILES;
    const size_t m0 = (size_t)mt * BM;

    // ---- A staging geometry: thread t covers row t>>2, fp32 cols (t&3)*16..+16
    const int rA = tid >> 2;                        // 0..255
    const float* xbase = X + (m0 + rA) * (size_t)H + (tid & 3) * 16;
    // A LDS dest: row-major [256][128B], byte col swizzled ^((row&7)<<4)
    const int aw0 = rA * 128 + ((((tid & 3) * 32)) ^ ((rA & 7) << 4));
    const int aw1 = rA * 128 + ((((tid & 3) * 32 + 16)) ^ ((rA & 7) << 4));
    // B staging: linear LDS dest (tid*16), source col pre-swizzled (rule 21)
    const int rB = tid >> 3;                        // 0..127
    const char* bG = (const char*)Bt + ((size_t)nt * BN + rB) * (size_t)(H * 2)
                     + (((tid & 7) * 16) ^ ((rB & 7) << 4));

    float4 va[4];
    float ssq = 0.f;

#define A_ISSUE(kt)                                                           \
    _Pragma("unroll") for (int j = 0; j < 4; ++j)                             \
        va[j] = *(const float4*)(xbase + (size_t)(kt) * 64 + j * 4);

#define A_CVTWRITE(buf)                                                       \
    {                                                                         \
        bf16x8 p0, p1;                                                        \
        _Pragma("unroll") for (int j = 0; j < 2; ++j) {                       \
            float4 f = va[j];                                                 \
            ssq += f.x * f.x + f.y * f.y + f.z * f.z + f.w * f.w;             \
            p0[j * 4 + 0] = f2bf(f.x); p0[j * 4 + 1] = f2bf(f.y);             \
            p0[j * 4 + 2] = f2bf(f.z); p0[j * 4 + 3] = f2bf(f.w);             \
        }                                                                     \
        _Pragma("unroll") for (int j = 0; j < 2; ++j) {                       \
            float4 f = va[j + 2];                                             \
            ssq += f.x * f.x + f.y * f.y + f.z * f.z + f.w * f.w;             \
            p1[j * 4 + 0] = f2bf(f.x); p1[j * 4 + 1] = f2bf(f.y);             \
            p1[j * 4 + 2] = f2bf(f.z); p1[j * 4 + 3] = f2bf(f.w);             \
        }                                                                     \
        *(bf16x8*)(smem + (size_t)(buf) * 49152 + aw0) = p0;                  \
        *(bf16x8*)(smem + (size_t)(buf) * 49152 + aw1) = p1;                  \
    }

#define STAGE_B(buf, kt)                                                      \
    GLOAD_LDS16(bG + (size_t)(kt) * (BK * 2),                                 \
                smem + (buf) * 49152 + 32768 + tid * 16);

    // ---- fragment read addressing (swizzled) ----
    const int rowA = wm * 64 + (lane & 15);
    const int rowB = wn * 32 + (lane & 15);
    const int xm = (lane & 7) << 4;
    const int c0 = (((lane >> 4) * 16)) ^ xm;
    const int c1 = (64 + ((lane >> 4) * 16)) ^ xm;

    f32x4 acc[4][2] = {};

#define COMPUTE(cur)                                                          \
    {                                                                         \
        const char* aL = smem + (cur) * 49152;                                \
        const char* bL = aL + 32768;                                          \
        bf16x8 b0[2], b1[2];                                                  \
        _Pragma("unroll") for (int ni = 0; ni < 2; ++ni) {                    \
            b0[ni] = *(const bf16x8*)(bL + (rowB + ni * 16) * 128 + c0);      \
            b1[ni] = *(const bf16x8*)(bL + (rowB + ni * 16) * 128 + c1);      \
        }                                                                     \
        __builtin_amdgcn_s_setprio(1);                                        \
        _Pragma("unroll") for (int mi = 0; mi < 4; ++mi) {                    \
            bf16x8 a = *(const bf16x8*)(aL + (rowA + mi * 16) * 128 + c0);    \
            _Pragma("unroll") for (int ni = 0; ni < 2; ++ni)                  \
                acc[mi][ni] = __builtin_amdgcn_mfma_f32_16x16x32_bf16(        \
                    a, b0[ni], acc[mi][ni], 0, 0, 0);                         \
        }                                                                     \
        _Pragma("unroll") for (int mi = 0; mi < 4; ++mi) {                    \
            bf16x8 a = *(const bf16x8*)(aL + (rowA + mi * 16) * 128 + c1);    \
            _Pragma("unroll") for (int ni = 0; ni < 2; ++ni)                  \
                acc[mi][ni] = __builtin_amdgcn_mfma_f32_16x16x32_bf16(        \
                    a, b1[ni], acc[mi][ni], 0, 0, 0);                         \
        }                                                                     \
        __builtin_amdgcn_s_setprio(0);                                        \
    }

#define TILE(cur, kt, DS, VM)                                                 \
    {                                                                         \
        if (DS) A_ISSUE((kt) + 2);                                            \
        COMPUTE(cur);                                                         \
        asm volatile("s_waitcnt vmcnt(" VM ") lgkmcnt(0)" ::: "memory");      \
        __builtin_amdgcn_sched_barrier(0);                                    \
        __builtin_amdgcn_s_barrier();                                         \
        __builtin_amdgcn_sched_barrier(0);                                    \
        if (DS) { STAGE_B(cur, (kt) + 2); A_CVTWRITE(cur); }                  \
    }

    // ---- prologue: stage tiles 0 and 1 ----
    A_ISSUE(0);
    STAGE_B(0, 0);
    A_CVTWRITE(0);                 // auto-vmcnt waits A(0) loads
    A_ISSUE(1);
    STAGE_B(1, 1);
    A_CVTWRITE(1);
    asm volatile("s_waitcnt vmcnt(0) lgkmcnt(0)" ::: "memory");
    __builtin_amdgcn_sched_barrier(0);
    __builtin_amdgcn_s_barrier();
    __builtin_amdgcn_sched_barrier(0);

    // ---- main loop: one barrier per K-tile, ring-2 ----
    for (int kt = 0; kt < NKT - 2; kt += 2) {
        TILE(0, kt, 1, "4");
        TILE(1, kt + 1, (kt + 1 < NKT - 2) ? 1 : 0, "4");
    }
    TILE(0, NKT - 2, 0, "0");
    TILE(1, NKT - 1, 0, "0");

    // ---- row scales: 4 staging threads per row hold partial sum(x^2) ----
    {
        float s = ssq;
        s += __shfl_xor(s, 1);
        s += __shfl_xor(s, 2);
        if ((tid & 3) == 0) s_lds[rA] = rsqrtf(s * (1.0f / H) + 1e-6f);
    }
    __syncthreads();

    // ---- epilogue: scale by s_r, split q/k/v regions ----
    const size_t QSZ = (size_t)rows * 1024;
    const size_t KSZ = (size_t)rows * 128;
    float* op;
    int ldc, cb0;
    if (nt < 8)       { op = out;             ldc = 1024; cb0 = nt * 128; }
    else if (nt == 8) { op = out + QSZ;       ldc = 128;  cb0 = 0; }
    else              { op = out + QSZ + KSZ; ldc = 128;  cb0 = 0; }

    const int rl0 = wm * 64 + ((lane >> 4) * 4);
    const size_t r0 = m0 + rl0;
    const int cc0 = cb0 + wn * 32 + (lane & 15);
#pragma unroll
    for (int mi = 0; mi < 4; ++mi)
#pragma unroll
        for (int r = 0; r < 4; ++r) {
            const float sc = s_lds[rl0 + mi * 16 + r];
#pragma unroll
            for (int ni = 0; ni < 2; ++ni)
                op[(r0 + mi * 16 + r) * (size_t)ldc + cc0 + ni * 16] =
                    acc[mi][ni][r] * sc;
        }
}

// ---------------------------------------------------------------------------
extern "C" void kernel_launch(void* const* d_in, const int* in_sizes, int n_in,
                              void* d_out, int out_size, void* d_ws, size_t ws_size,
                              hipStream_t stream) {
    const float* x   = (const float*)d_in[0];
    const float* lnw = (const float*)d_in[1];
    const float* wq  = (const float*)d_in[2];
    const float* wk  = (const float*)d_in[3];
    const float* wv  = (const float*)d_in[4];
    float* out = (float*)d_out;

    const int rows = in_sizes[0] / H;  // B*S = 32768

    __hip_bfloat16* Bt = (__hip_bfloat16*)d_ws;  // 1280*1024*2 = 2.62 MB

    k_wprep<<<NTOT * H / 256, 256, 0, stream>>>(wq, wk, wv, lnw, Bt);
    k_gemm<<<(rows / BM) * NTILES, 1024, 0, stream>>>(x, Bt, out, rows);
}